// Round 4
// baseline (182.366 us; speedup 1.0000x reference)
//
#include <hip/hip_runtime.h>
#include <math.h>

#define Bn 4
#define Cn 64
#define On 64
#define Hn 128
#define Wn 128
#define HWn (Hn * Wn)

typedef __attribute__((ext_vector_type(8))) short s16x8;
typedef __attribute__((ext_vector_type(4))) float f32x4;

__device__ __forceinline__ unsigned short f2bf(float f) {
    unsigned u = __float_as_uint(f);
    u += 0x7fffu + ((u >> 16) & 1u);  // RTNE (finite values)
    return (unsigned short)(u >> 16);
}
__device__ __forceinline__ float bf2f(unsigned short u) {
    return __uint_as_float(((unsigned)u) << 16);
}

// ---------------------------------------------------------------------------
// Kernel 1: [B,C,H,W] f32 -> [B,HW,C] bf16, for BOTH x and feat (blockIdx.z).
// ---------------------------------------------------------------------------
__global__ __launch_bounds__(256) void transpose_in_kernel(const float* __restrict__ x,
                                                           const float* __restrict__ feat,
                                                           ushort* __restrict__ xt,
                                                           ushort* __restrict__ ft) {
    __shared__ float tile[64][65];
    const float* src = blockIdx.z ? feat : x;
    ushort* dst0 = blockIdx.z ? ft : xt;
    int b = blockIdx.y, hw0 = blockIdx.x * 64, t = threadIdx.x;
    int lane = t & 63, grp = t >> 6;
    const float* xb = src + (size_t)b * Cn * HWn;
#pragma unroll
    for (int i = 0; i < 16; ++i) {
        int c = grp * 16 + i;
        tile[lane][c] = xb[(size_t)c * HWn + hw0 + lane];  // coalesced along hw
    }
    __syncthreads();
    int hw = t & 63, c0 = (t >> 6) * 16;
    ushort* dst = dst0 + ((size_t)(b * HWn + hw0 + hw)) * Cn + c0;
    s16x8 p0, p1;
#pragma unroll
    for (int j = 0; j < 8; ++j) {
        p0[j] = (short)f2bf(tile[hw][c0 + j]);
        p1[j] = (short)f2bf(tile[hw][c0 + 8 + j]);
    }
    *(s16x8*)dst = p0;
    *(s16x8*)(dst + 8) = p1;
}

// ---------------------------------------------------------------------------
// Kernel 2: weights -> bf16, [k][oc][c] layouts.
// ---------------------------------------------------------------------------
__global__ __launch_bounds__(256) void transpose_w_kernel(const float* __restrict__ wdef,
                                                          const float* __restrict__ woff,
                                                          ushort* __restrict__ wdT,
                                                          ushort* __restrict__ woT) {
    int idx = blockIdx.x * 256 + threadIdx.x;
    if (idx < 9 * 64 * 64) {
        int c = idx & 63, oc = (idx >> 6) & 63, k = idx >> 12;
        wdT[idx] = f2bf(wdef[(oc * 64 + c) * 9 + k]);
    } else if (idx < 9 * 64 * 64 + 9 * 32 * 64) {
        int i2 = idx - 9 * 64 * 64;
        int c = i2 & 63, oc = (i2 >> 6) & 31, k = i2 >> 11;
        woT[i2] = (oc < 27) ? f2bf(woff[(oc * 64 + c) * 9 + k]) : (ushort)0;
    }
}

// ---------------------------------------------------------------------------
// Mega kernel: 256 threads = 4 independent waves; block = 64 contiguous px
// (one half-row), wave wv owns px [w0, w0+16). Phase 1: offset conv via MFMA
// from channels-last bf16 feat (b128 loads, no cvt). Phase 2: bilinear
// sampling -> register A-frags -> MFMA vs L2-resident wdT.
// A-frag layout: m=lane&15, k=(lane>>4)*8+j. C/D: col=lane&15, row=(lane>>4)*4+reg.
// ---------------------------------------------------------------------------
__global__ __launch_bounds__(256, 4) void mega_kernel(const ushort* __restrict__ ft,
                                                      const ushort* __restrict__ xt,
                                                      const ushort* __restrict__ woT,
                                                      const ushort* __restrict__ wdT,
                                                      const float* __restrict__ b_off,
                                                      const float* __restrict__ b_def,
                                                      float* __restrict__ out) {
    __shared__ __align__(16) float smem[64 * 68];  // s_om slices (4x528) / s_out [64][68]

    int t = threadIdx.x;
    int wv = t >> 6, l = t & 63;
    int q = l >> 4, r = l & 15;
    int p0 = blockIdx.x * 64;
    int b = p0 >> 14;              // / HWn
    int rem = p0 & (HWn - 1);
    int h = rem >> 7;              // / Wn
    int wbase = rem & (Wn - 1);    // 0 or 64
    int w0 = wbase + wv * 16;      // this wave's px base

    float* s_om = smem + wv * 528;  // [16][33] wave-private
    float* s_out = smem;            // [64][68] block-shared (epilogue)

    f32x4 zero = {0.f, 0.f, 0.f, 0.f};
    s16x8 zz = {0, 0, 0, 0, 0, 0, 0, 0};

    // ================= Phase 1: offset conv (16px x 32oc) =================
    f32x4 acc2[2];
    acc2[0] = zero; acc2[1] = zero;
#pragma unroll 1
    for (int k = 0; k < 9; ++k) {
        int dy = k / 3 - 1, dx = k % 3 - 1;
        int y = h + dy;
        int xx = w0 + r + dx;
        bool valid = (y >= 0) && (y < Hn) && (xx >= 0) && (xx < Wn);
        int off = (b * HWn + y * Wn + xx) * Cn;
#pragma unroll
        for (int s = 0; s < 2; ++s) {
            int c = s * 32 + q * 8;
            s16x8 av = valid ? *(const s16x8*)(ft + off + c) : zz;
#pragma unroll
            for (int ot = 0; ot < 2; ++ot) {
                s16x8 bw = *(const s16x8*)(woT + ((k * 32 + ot * 16 + r) * 64 + c));
                acc2[ot] = __builtin_amdgcn_mfma_f32_16x16x32_bf16(av, bw, acc2[ot], 0, 0, 0);
            }
        }
    }
    // bias + sigmoid(mask planes); redistribute to s_om[px][oc]
#pragma unroll
    for (int ot = 0; ot < 2; ++ot) {
        int oc = ot * 16 + r;
        float bo = (oc < 27) ? b_off[oc] : 0.f;
#pragma unroll
        for (int reg = 0; reg < 4; ++reg) {
            int px = q * 4 + reg;
            float v = acc2[ot][reg] + bo;
            if (oc >= 18 && oc < 27) v = 1.f / (1.f + __expf(-v));
            s_om[px * 33 + oc] = v;
        }
    }
    __syncthreads();

    // ================= Phase 2: sampling + main GEMM (16px x 64oc) =========
    f32x4 acc[4];
#pragma unroll
    for (int i = 0; i < 4; ++i) acc[i] = zero;

    const int bb = b * HWn * Cn;
    const float* omr = s_om + r * 33;

#pragma unroll 2
    for (int k = 0; k < 9; ++k) {
        int dy = k / 3 - 1, dx = k % 3 - 1;
        float offx = omr[k];
        float offy = omr[9 + k];
        float mv = omr[18 + k];
        float ys = (float)(h + dy) + offy;
        float xs = (float)(w0 + r + dx) + offx;
        float y0f = floorf(ys), x0f = floorf(xs);
        float fy = ys - y0f, fx = xs - x0f;
        int y0 = (int)y0f, x0 = (int)x0f;
        float g[4];
        int a[4];
#pragma unroll
        for (int n = 0; n < 4; ++n) {
            int yy = y0 + (n >> 1), xx = x0 + (n & 1);
            bool valid = (yy >= 0) && (yy < Hn) && (xx >= 0) && (xx < Wn);
            float wgt = ((n >> 1) ? fy : 1.f - fy) * ((n & 1) ? fx : 1.f - fx) * mv;
            g[n] = valid ? wgt : 0.f;
            int yc = min(max(yy, 0), Hn - 1), xc = min(max(xx, 0), Wn - 1);
            a[n] = bb + (yc * Wn + xc) * Cn;
        }
        // issue all 8 gather loads, then combine
        s16x8 qv[2][4];
#pragma unroll
        for (int s = 0; s < 2; ++s) {
            int c = s * 32 + q * 8;
#pragma unroll
            for (int n = 0; n < 4; ++n) qv[s][n] = *(const s16x8*)(xt + a[n] + c);
        }
        s16x8 af[2];
#pragma unroll
        for (int s = 0; s < 2; ++s) {
            s16x8 p;
#pragma unroll
            for (int j = 0; j < 8; ++j) {
                float rr = g[0] * bf2f((unsigned short)qv[s][0][j])
                         + g[1] * bf2f((unsigned short)qv[s][1][j])
                         + g[2] * bf2f((unsigned short)qv[s][2][j])
                         + g[3] * bf2f((unsigned short)qv[s][3][j]);
                p[j] = (short)f2bf(rr);
            }
            af[s] = p;
        }
#pragma unroll
        for (int s = 0; s < 2; ++s) {
            int c = s * 32 + q * 8;
#pragma unroll
            for (int ot = 0; ot < 4; ++ot) {
                s16x8 bw = *(const s16x8*)(wdT + ((k * 64 + ot * 16 + r) * 64 + c));
                acc[ot] = __builtin_amdgcn_mfma_f32_16x16x32_bf16(af[s], bw, acc[ot], 0, 0, 0);
            }
        }
    }
    __syncthreads();  // all waves done with s_om; smem becomes s_out

    // ================= Epilogue: bias + ReLU, coalesced store ===============
#pragma unroll
    for (int ot = 0; ot < 4; ++ot) {
        int oc = ot * 16 + r;
        float bv = b_def[oc];
        f32x4 vv;
#pragma unroll
        for (int reg = 0; reg < 4; ++reg) vv[reg] = fmaxf(acc[ot][reg] + bv, 0.f);
        *(f32x4*)&s_out[oc * 68 + wv * 16 + q * 4] = vv;  // px = wv*16 + q*4 + reg
    }
    __syncthreads();
    {
        int px = t & 63, og = t >> 6;
        float* ob = out + ((size_t)b * On) * HWn + h * Wn + wbase;
#pragma unroll
        for (int j = 0; j < 16; ++j) {
            int oc = og * 16 + j;
            ob[(size_t)oc * HWn + px] = s_out[oc * 68 + px];
        }
    }
}

// ---------------------------------------------------------------------------
extern "C" void kernel_launch(void* const* d_in, const int* in_sizes, int n_in,
                              void* d_out, int out_size, void* d_ws, size_t ws_size,
                              hipStream_t stream) {
    const float* x = (const float*)d_in[0];
    const float* feat = (const float*)d_in[1];
    const float* w_off = (const float*)d_in[2];
    const float* b_off = (const float*)d_in[3];
    const float* w_def = (const float*)d_in[4];
    const float* b_def = (const float*)d_in[5];
    float* out = (float*)d_out;

    char* ws = (char*)d_ws;
    ushort* xt = (ushort*)ws;                              // 8 MB: [B,HW,C] bf16
    ushort* ft = (ushort*)(ws + 8388608);                  // 8 MB: [B,HW,C] bf16
    ushort* wdT = (ushort*)(ws + 16777216);                // 72 KB: [9,64,64] bf16
    ushort* woT = (ushort*)(ws + 16777216 + 73728);        // 36 KB: [9,32,64] bf16

    hipLaunchKernelGGL(transpose_in_kernel, dim3(HWn / 64, Bn, 2), dim3(256), 0, stream,
                       x, feat, xt, ft);
    hipLaunchKernelGGL(transpose_w_kernel, dim3(216), dim3(256), 0, stream, w_def, w_off, wdT, woT);
    hipLaunchKernelGGL(mega_kernel, dim3((Bn * HWn) / 64), dim3(256), 0, stream,
                       ft, xt, woT, wdT, b_off, b_def, out);
}

// Round 5
// 146.705 us; speedup vs baseline: 1.2431x; 1.2431x over previous
//
#include <hip/hip_runtime.h>
#include <math.h>

#define Bn 4
#define Cn 64
#define On 64
#define Hn 128
#define Wn 128
#define HWn (Hn * Wn)

#define WCOLS 68   // window cols: x0r in [-2,64]
#define WROWS 5    // window rows: y0r in [-2,1]

typedef __attribute__((ext_vector_type(8))) short s16x8;
typedef __attribute__((ext_vector_type(4))) float f32x4;

__device__ __forceinline__ unsigned short f2bf(float f) {
    unsigned u = __float_as_uint(f);
    u += 0x7fffu + ((u >> 16) & 1u);  // RTNE (finite values)
    return (unsigned short)(u >> 16);
}
__device__ __forceinline__ float bf2f(unsigned short u) {
    return __uint_as_float(((unsigned)u) << 16);
}

// ---------------------------------------------------------------------------
// Kernel 1: all input prep in one launch.
// z=0: x -> xt [B,HW,C] bf16 ; z=1: feat -> ft ; z=2: weights -> wdT/woT.
// ---------------------------------------------------------------------------
__global__ __launch_bounds__(256) void transpose_all(const float* __restrict__ x,
                                                     const float* __restrict__ feat,
                                                     const float* __restrict__ wdef,
                                                     const float* __restrict__ woff,
                                                     ushort* __restrict__ xt,
                                                     ushort* __restrict__ ft,
                                                     ushort* __restrict__ wdT,
                                                     ushort* __restrict__ woT) {
    int t = threadIdx.x;
    if (blockIdx.z == 2) {
        int id = (blockIdx.y * gridDim.x + blockIdx.x) * 256 + t;
        if (id < 36864) {
            int c = id & 63, oc = (id >> 6) & 63, k = id >> 12;
            wdT[id] = f2bf(wdef[(oc * 64 + c) * 9 + k]);
        } else if (id < 55296) {
            int i2 = id - 36864;
            int c = i2 & 63, oc = (i2 >> 6) & 31, k = i2 >> 11;
            woT[i2] = (oc < 27) ? f2bf(woff[(oc * 64 + c) * 9 + k]) : (ushort)0;
        }
        return;
    }
    __shared__ float tile[64][65];
    const float* src = blockIdx.z ? feat : x;
    ushort* dst0 = blockIdx.z ? ft : xt;
    int b = blockIdx.y, hw0 = blockIdx.x * 64;
    int lane = t & 63, grp = t >> 6;
    const float* xb = src + (size_t)b * Cn * HWn;
#pragma unroll
    for (int i = 0; i < 16; ++i) {
        int c = grp * 16 + i;
        tile[lane][c] = xb[(size_t)c * HWn + hw0 + lane];  // coalesced along hw
    }
    __syncthreads();
#pragma unroll
    for (int jj = 0; jj < 2; ++jj) {
        int px = jj * 32 + (t >> 3), ch = t & 7;
        s16x8 p;
#pragma unroll
        for (int j = 0; j < 8; ++j) p[j] = (short)f2bf(tile[px][ch * 8 + j]);
        *(s16x8*)(dst0 + ((size_t)(b * HWn + hw0 + px)) * Cn + ch * 8) = p;  // coalesced
    }
}

// ---------------------------------------------------------------------------
// Mega kernel: block = 64 px (half row), 4 waves x 16 px. LDS-window design:
//  - stage ft rows h-1..h+1 (window rows 1..3) -> phase-1 offset conv (MFMA)
//  - offsets/mask -> registers (omv[27]/lane) via transient LDS transpose
//  - stage xt rows h-2..h+2 + wdT tap0; block-uniform fast/slow vote
//  - fast: bilinear gathers from LDS window (XOR-swizzled, conflict-free),
//    weights from LDS double-buffer (1 barrier/tap)
//  - slow (rare, any-input correct): R4 global-gather path
// Window addressing: px lin = row*68+col, ushort addr = lin*64 + ((chunk^(lin&7))*8).
// Weight buf: addr = oc*64 + ((chunk^(oc&7))*8).
// ---------------------------------------------------------------------------
__global__ __launch_bounds__(256, 2) void mega_kernel(const ushort* __restrict__ ft,
                                                      const ushort* __restrict__ xt,
                                                      const ushort* __restrict__ woT,
                                                      const ushort* __restrict__ wdT,
                                                      const float* __restrict__ b_off,
                                                      const float* __restrict__ b_def,
                                                      float* __restrict__ out) {
    __shared__ __align__(16) char smem[59936];
    ushort* s_win = (ushort*)smem;               // 43520 B: [5][68] px, swizzled
    ushort* s_wb = (ushort*)(smem + 43520);      // 16384 B: 2 x [64 oc][64 c] swizzled
    int* s_flag = (int*)(smem + 59904);          // 4 ints
    float* s_omt = (float*)smem;                 // 7168 B transient (disjoint from rows 1..4)
    float* s_out = (float*)smem;                 // 17408 B epilogue

    int t = threadIdx.x;
    int wv = t >> 6, l = t & 63;
    int q = l >> 4, r = l & 15;
    int p0 = blockIdx.x * 64;
    int b = p0 >> 14;
    int rem = p0 & (HWn - 1);
    int h = rem >> 7;
    int wbase = rem & (Wn - 1);
    int pxi = wv * 16 + r;

    const ushort* xt_b = xt + (size_t)b * HWn * Cn;
    const ushort* ft_b = ft + (size_t)b * HWn * Cn;

    f32x4 zero = {0.f, 0.f, 0.f, 0.f};
    s16x8 zz = {0, 0, 0, 0, 0, 0, 0, 0};

    // ---- stage ft window rows 1..3 (image rows h-1..h+1, clamped) ----
#pragma unroll
    for (int i = 1; i <= 3; ++i) {
        int rs = min(max(h - 2 + i, 0), Hn - 1);
        for (int j = t; j < WCOLS * 8; j += 256) {
            int col = j >> 3, ch = j & 7;
            int cs = min(max(wbase - 2 + col, 0), Wn - 1);
            s16x8 v = *(const s16x8*)(ft_b + (size_t)(rs * Wn + cs) * Cn + ch * 8);
            int lin = i * WCOLS + col;
            *(s16x8*)&s_win[(size_t)lin * 64 + ((ch ^ (lin & 7)) << 3)] = v;
        }
    }
    __syncthreads();

    // ---- Phase 1: offset conv (16px x 32oc per wave), weights from global ----
    f32x4 acc2[2];
    acc2[0] = zero; acc2[1] = zero;
#pragma unroll
    for (int k = 0; k < 9; ++k) {
        const int dy = k / 3 - 1, dx = k % 3 - 1;
        int yab = h + dy, xab = wbase + pxi + dx;
        bool valid = (yab >= 0) && (yab < Hn) && (xab >= 0) && (xab < Wn);
        int lin = (dy + 2) * WCOLS + (pxi + dx + 2);
#pragma unroll
        for (int s = 0; s < 2; ++s) {
            s16x8 av = *(const s16x8*)&s_win[(size_t)lin * 64 + (((s * 4 + q) ^ (lin & 7)) << 3)];
            av = valid ? av : zz;
#pragma unroll
            for (int ot = 0; ot < 2; ++ot) {
                s16x8 bw = *(const s16x8*)(woT + (size_t)((k * 32 + ot * 16 + r) * 64 + s * 32 + q * 8));
                acc2[ot] = __builtin_amdgcn_mfma_f32_16x16x32_bf16(av, bw, acc2[ot], 0, 0, 0);
            }
        }
    }
    __syncthreads();  // A: all phase-1 window reads (bytes >= 8704) done

    // omt transpose (bytes 0..7167; disjoint from phase-1-read region)
#pragma unroll
    for (int ot = 0; ot < 2; ++ot) {
        int oc = ot * 16 + r;
        if (oc < 27) {
            float bo = b_off[oc];
#pragma unroll
            for (int reg = 0; reg < 4; ++reg) {
                float v = acc2[ot][reg] + bo;
                if (oc >= 18) v = 1.f / (1.f + __expf(-v));
                s_omt[(wv * 16 + q * 4 + reg) * 28 + oc] = v;  // wave-private slice
            }
        }
    }
    // own-wave LDS write->read; lgkmcnt ordering suffices (same wave)
    float omv[27];
    {
        const float* srcp = s_omt + (wv * 16 + r) * 28;
#pragma unroll
        for (int o = 0; o < 27; ++o) omv[o] = srcp[o];
    }
    // fast/slow predicate: all samples inside the 5x68 window
    bool okp = true;
    float pxif = (float)pxi;
#pragma unroll
    for (int k = 0; k < 9; ++k) {
        const float dyf = (float)(k / 3 - 1), dxf = (float)(k % 3 - 1);
        float uy = dyf + omv[9 + k];
        float ux = pxif + dxf + omv[k];
        okp = okp && (uy >= -2.f) && (uy < 2.f) && (ux >= -2.f) && (ux < 65.f);
    }
    int allok = __all(okp) ? 1 : 0;
    if (l == 0) s_flag[wv] = allok;
    __syncthreads();  // B: omv reads done; safe to overwrite window

    // ---- stage x window rows 0..4 + wdT tap 0 into buf 0 ----
#pragma unroll
    for (int i = 0; i < WROWS; ++i) {
        int rs = min(max(h - 2 + i, 0), Hn - 1);
        for (int j = t; j < WCOLS * 8; j += 256) {
            int col = j >> 3, ch = j & 7;
            int cs = min(max(wbase - 2 + col, 0), Wn - 1);
            s16x8 v = *(const s16x8*)(xt_b + (size_t)(rs * Wn + cs) * Cn + ch * 8);
            int lin = i * WCOLS + col;
            *(s16x8*)&s_win[(size_t)lin * 64 + ((ch ^ (lin & 7)) << 3)] = v;
        }
    }
    int woc = t >> 3, wch = t & 7;
    int wsw = (wch ^ (woc & 7)) << 3;
    {
        s16x8 v0 = *(const s16x8*)(wdT + (size_t)woc * 64 + wch * 8);
        s16x8 v1 = *(const s16x8*)(wdT + (size_t)(woc + 32) * 64 + wch * 8);
        *(s16x8*)&s_wb[woc * 64 + wsw] = v0;
        *(s16x8*)&s_wb[(woc + 32) * 64 + wsw] = v1;
    }
    __syncthreads();  // C

    int fast = s_flag[0] & s_flag[1] & s_flag[2] & s_flag[3];

    f32x4 acc[4];
    acc[0] = zero; acc[1] = zero; acc[2] = zero; acc[3] = zero;

    if (fast) {
#pragma unroll
        for (int k = 0; k < 9; ++k) {
            // prefetch next tap's weights (global -> regs)
            s16x8 pf0, pf1;
            if (k < 8) {
                const ushort* srcw = wdT + (size_t)(k + 1) * 4096;
                pf0 = *(const s16x8*)(srcw + woc * 64 + wch * 8);
                pf1 = *(const s16x8*)(srcw + (woc + 32) * 64 + wch * 8);
            }
            const int dyk = k / 3 - 1, dxk = k % 3 - 1;
            float uy = (float)dyk + omv[9 + k];
            float ux = pxif + (float)dxk + omv[k];
            float mv = omv[18 + k];
            float y0f = floorf(uy), x0f = floorf(ux);
            float fy = uy - y0f, fx = ux - x0f;
            int iy = (int)y0f + 2;  // 0..3
            int ix = (int)x0f + 2;  // 0..66
            int yab = h + (int)y0f, xab = wbase + (int)x0f;
            bool vy0 = (yab >= 0) && (yab < Hn), vy1 = (yab + 1 >= 0) && (yab + 1 < Hn);
            bool vx0 = (xab >= 0) && (xab < Wn), vx1 = (xab + 1 >= 0) && (xab + 1 < Wn);
            float g[4];
            g[0] = (vy0 && vx0) ? (1.f - fy) * (1.f - fx) * mv : 0.f;
            g[1] = (vy0 && vx1) ? (1.f - fy) * fx * mv : 0.f;
            g[2] = (vy1 && vx0) ? fy * (1.f - fx) * mv : 0.f;
            g[3] = (vy1 && vx1) ? fy * fx * mv : 0.f;
            int lin0 = iy * WCOLS + ix;
            int lins[4] = {lin0, lin0 + 1, lin0 + WCOLS, lin0 + WCOLS + 1};
            s16x8 qv[2][4];
#pragma unroll
            for (int s = 0; s < 2; ++s)
#pragma unroll
                for (int n = 0; n < 4; ++n) {
                    int lin = lins[n];
                    qv[s][n] = *(const s16x8*)&s_win[(size_t)lin * 64 + (((s * 4 + q) ^ (lin & 7)) << 3)];
                }
            s16x8 af[2];
#pragma unroll
            for (int s = 0; s < 2; ++s) {
                s16x8 p;
#pragma unroll
                for (int j = 0; j < 8; ++j) {
                    float rr = g[0] * bf2f((unsigned short)qv[s][0][j])
                             + g[1] * bf2f((unsigned short)qv[s][1][j])
                             + g[2] * bf2f((unsigned short)qv[s][2][j])
                             + g[3] * bf2f((unsigned short)qv[s][3][j]);
                    p[j] = (short)f2bf(rr);
                }
                af[s] = p;
            }
            const ushort* wb = s_wb + (k & 1) * 4096;
#pragma unroll
            for (int s = 0; s < 2; ++s)
#pragma unroll
                for (int ot = 0; ot < 4; ++ot) {
                    s16x8 bw = *(const s16x8*)&wb[(ot * 16 + r) * 64 + (((s * 4 + q) ^ (r & 7)) << 3)];
                    acc[ot] = __builtin_amdgcn_mfma_f32_16x16x32_bf16(af[s], bw, acc[ot], 0, 0, 0);
                }
            if (k < 8) {
                ushort* wb1 = s_wb + ((k + 1) & 1) * 4096;
                *(s16x8*)&wb1[woc * 64 + wsw] = pf0;
                *(s16x8*)&wb1[(woc + 32) * 64 + wsw] = pf1;
                __syncthreads();
            }
        }
    } else {
        // ---- slow path: any-input-correct global gathers (R4 structure) ----
#pragma unroll 1
        for (int k = 0; k < 9; ++k) {
            int dyk = k / 3 - 1, dxk = k % 3 - 1;
            float offx = omv[k], offy = omv[9 + k], mv = omv[18 + k];
            float ys = (float)(h + dyk) + offy;
            float xs = (float)(wbase + pxi + dxk) + offx;
            float y0f = floorf(ys), x0f = floorf(xs);
            float fy = ys - y0f, fx = xs - x0f;
            int y0 = (int)y0f, x0 = (int)x0f;
            float g[4];
            int a[4];
#pragma unroll
            for (int n = 0; n < 4; ++n) {
                int yy = y0 + (n >> 1), xx = x0 + (n & 1);
                bool valid = (yy >= 0) && (yy < Hn) && (xx >= 0) && (xx < Wn);
                float wgt = ((n >> 1) ? fy : 1.f - fy) * ((n & 1) ? fx : 1.f - fx) * mv;
                g[n] = valid ? wgt : 0.f;
                int yc = min(max(yy, 0), Hn - 1), xc = min(max(xx, 0), Wn - 1);
                a[n] = (yc * Wn + xc) * Cn;
            }
            s16x8 qv[2][4];
#pragma unroll
            for (int s = 0; s < 2; ++s) {
                int c = s * 32 + q * 8;
#pragma unroll
                for (int n = 0; n < 4; ++n) qv[s][n] = *(const s16x8*)(xt_b + a[n] + c);
            }
            s16x8 af[2];
#pragma unroll
            for (int s = 0; s < 2; ++s) {
                s16x8 p;
#pragma unroll
                for (int j = 0; j < 8; ++j) {
                    float rr = g[0] * bf2f((unsigned short)qv[s][0][j])
                             + g[1] * bf2f((unsigned short)qv[s][1][j])
                             + g[2] * bf2f((unsigned short)qv[s][2][j])
                             + g[3] * bf2f((unsigned short)qv[s][3][j]);
                    p[j] = (short)f2bf(rr);
                }
                af[s] = p;
            }
#pragma unroll
            for (int s = 0; s < 2; ++s) {
                int c = s * 32 + q * 8;
#pragma unroll
                for (int ot = 0; ot < 4; ++ot) {
                    s16x8 bw = *(const s16x8*)(wdT + (size_t)((k * 64 + ot * 16 + r) * 64 + c));
                    acc[ot] = __builtin_amdgcn_mfma_f32_16x16x32_bf16(af[s], bw, acc[ot], 0, 0, 0);
                }
            }
        }
    }
    __syncthreads();  // join: window reads done; smem becomes s_out

    // ---- Epilogue: bias + ReLU, stage [oc][px], coalesced store ----
#pragma unroll
    for (int ot = 0; ot < 4; ++ot) {
        int oc = ot * 16 + r;
        float bv = b_def[oc];
        f32x4 vv;
#pragma unroll
        for (int reg = 0; reg < 4; ++reg) vv[reg] = fmaxf(acc[ot][reg] + bv, 0.f);
        *(f32x4*)&s_out[oc * 68 + wv * 16 + q * 4] = vv;
    }
    __syncthreads();
    {
        int px = t & 63, og = t >> 6;
        float* ob = out + ((size_t)b * On) * HWn + h * Wn + wbase;
#pragma unroll
        for (int j = 0; j < 16; ++j) {
            int oc = og * 16 + j;
            ob[(size_t)oc * HWn + px] = s_out[oc * 68 + px];
        }
    }
}

// ---------------------------------------------------------------------------
extern "C" void kernel_launch(void* const* d_in, const int* in_sizes, int n_in,
                              void* d_out, int out_size, void* d_ws, size_t ws_size,
                              hipStream_t stream) {
    const float* x = (const float*)d_in[0];
    const float* feat = (const float*)d_in[1];
    const float* w_off = (const float*)d_in[2];
    const float* b_off = (const float*)d_in[3];
    const float* w_def = (const float*)d_in[4];
    const float* b_def = (const float*)d_in[5];
    float* out = (float*)d_out;

    char* ws = (char*)d_ws;
    ushort* xt = (ushort*)ws;                          // 8 MB: [B,HW,C] bf16
    ushort* ft = (ushort*)(ws + 8388608);              // 8 MB: [B,HW,C] bf16
    ushort* wdT = (ushort*)(ws + 16777216);            // 72 KB: [9,64,64] bf16
    ushort* woT = (ushort*)(ws + 16777216 + 73728);    // 36 KB: [9,32,64] bf16

    hipLaunchKernelGGL(transpose_all, dim3(HWn / 64, Bn, 3), dim3(256), 0, stream,
                       x, feat, w_def, w_off, xt, ft, wdT, woT);
    hipLaunchKernelGGL(mega_kernel, dim3((Bn * HWn) / 64), dim3(256), 0, stream,
                       ft, xt, woT, wdT, b_off, b_def, out);
}